// Round 9
// baseline (45.921 us; speedup 1.0000x reference)
//
#include <hip/hip_runtime.h>
#include <stdint.h>

// VQ-VAE quantization: B=131072 rows of z (D=64) vs N_E=1024 codes.
// Outputs (flat f32): z_q [131072*64] | loss [1] | idx [131072] | var(idx,ddof=1) [1]
//
// R9: 8-wave blocks (halves per-CU staging + LDS-read redundancy vs R8),
// triple-buffered LDS with ONE barrier per phase (stage ph+2 after the
// barrier that retires ph-1's readers), counted vmcnt(2), setprio around
// MFMA, exact-order keys: key = (float_bits(t) << 10) + n with C-in
// t = 0.875 + ||e||^2 - 2 z.e  in [0.75,1) so sign/exp/mant22 are constant
// and shift out; unsigned min == exact (distance, index) argmin.

typedef __attribute__((ext_vector_type(8))) __bf16 bf16x8;
typedef __attribute__((ext_vector_type(4))) float f32x4;

#define OUT_LOSS 8388608
#define OUT_IDX  8388609
#define OUT_VAR  8519681

// workspace layout (bytes)
#define WS_LOSS  0          // float[512] per-block loss partials
#define WS_S1    4096       // int[512] sum(idx)
#define WS_S2    8192       // int[512] sum(idx^2)
#define WS_EFRAG 12288      // bf16x8[64 tiles * 2 ksteps * 64 lanes] = 128 KB
#define WS_EE    143360     // float[1024] ||e||^2 + 0.875 (4 KB)

__device__ __forceinline__ void gld_lds16(const void* g, void* l) {
  __builtin_amdgcn_global_load_lds(
      (const __attribute__((address_space(1))) unsigned*)g,
      (__attribute__((address_space(3))) unsigned*)l, 16, 0, 0);
}

// ---- K0: prep codebook fragments -----------------------------------------
// A-frag for mfma_f32_16x16x32_bf16: lane l holds code row (t*16 + (l&15)),
// k = kstep*32 + (l>>4)*8 + i. Values are -2*e.
__global__ void vq_prep(const float* __restrict__ emb, char* __restrict__ ws) {
  bf16x8* efrag = (bf16x8*)(ws + WS_EFRAG);
  float* eeoff = (float*)(ws + WS_EE);
  const int t = blockIdx.x;    // tile 0..63
  const int l = threadIdx.x;   // 0..63
  const int n = t * 16 + (l & 15);
  const int kb0 = (l >> 4) * 8;
  const float* er = emb + n * 64;
  for (int j = 0; j < 2; ++j) {
    const int kb = j * 32 + kb0;
    bf16x8 h;
#pragma unroll
    for (int i = 0; i < 8; ++i) h[i] = (__bf16)(-2.0f * er[kb + i]);
    efrag[(t * 2 + j) * 64 + l] = h;
  }
  if (l < 16) {
    const float* e2 = emb + (t * 16 + l) * 64;
    float s = 0.f;
#pragma unroll
    for (int d = 0; d < 64; ++d) s += e2[d] * e2[d];
    eeoff[t * 16 + l] = s + 0.875f;   // keeps t in [0.75, 1): |2 z.e| << 0.125
  }
}

// ---- K1: distances + argmin + fused epilogue ------------------------------
// 512 blocks x 512 thr (8 waves); wave w owns rows blockIdx*256 + w*32 .. +31.
__global__ void __launch_bounds__(512) vq_main(
    const float* __restrict__ z, const float* __restrict__ emb,
    float* __restrict__ out, char* __restrict__ ws) {
  __shared__ char smfrag[3][16384];   // triple-buffered 8-tile phases
  __shared__ float see[1024];         // ||e||^2 + 0.875 table
  __shared__ float sL[8];
  __shared__ int sA[8], sB[8];

  const int tid = threadIdx.x;
  const int wave = tid >> 6, lane = tid & 63;
  const int lr = lane & 15, ksl = lane >> 4;
  const int k0 = ksl * 8;
  const int row_base = blockIdx.x * 256 + wave * 32;

#define STAGE(ph, buf)                                                          \
  {                                                                             \
    _Pragma("unroll")                                                           \
    for (int i_ = 0; i_ < 2; ++i_)                                              \
      gld_lds16(ws + WS_EFRAG + (ph) * 16384 + wave * 2048 + i_ * 1024 + lane * 16, \
                smfrag[buf] + wave * 2048 + i_ * 1024);                         \
  }

  // z loads FIRST (oldest in vmcnt queue, so the compiler's waits for their
  // consumers leave the staging loads in flight).
  const float* zra = z + (size_t)(row_base + lr) * 64;
  const float* zrb = z + (size_t)(row_base + 16 + lr) * 64;
  f32x4 a0 = *(const f32x4*)(zra + k0);
  f32x4 a1 = *(const f32x4*)(zra + k0 + 4);
  f32x4 a2 = *(const f32x4*)(zra + 32 + k0);
  f32x4 a3 = *(const f32x4*)(zra + 32 + k0 + 4);
  f32x4 b0 = *(const f32x4*)(zrb + k0);
  f32x4 b1 = *(const f32x4*)(zrb + k0 + 4);
  f32x4 b2 = *(const f32x4*)(zrb + 32 + k0);
  f32x4 b3 = *(const f32x4*)(zrb + 32 + k0 + 4);

  // async staging: ee table (waves 0-3) + phases 0,1
  if (wave < 4)
    gld_lds16(ws + WS_EE + wave * 1024 + lane * 16, (char*)see + wave * 1024);
  STAGE(0, 0);
  STAGE(1, 1);

  // convert z to bf16 B-fragments + ||z||^2 (overlaps staging latency)
  bf16x8 zfa0, zfa1, zfb0, zfb1;
  float zza, zzb;
  {
    float sa = 0.f, sb = 0.f;
#pragma unroll
    for (int i = 0; i < 4; ++i) {
      zfa0[i] = (__bf16)a0[i]; zfa0[4 + i] = (__bf16)a1[i];
      zfa1[i] = (__bf16)a2[i]; zfa1[4 + i] = (__bf16)a3[i];
      zfb0[i] = (__bf16)b0[i]; zfb0[4 + i] = (__bf16)b1[i];
      zfb1[i] = (__bf16)b2[i]; zfb1[4 + i] = (__bf16)b3[i];
      sa += a0[i] * a0[i] + a1[i] * a1[i] + a2[i] * a2[i] + a3[i] * a3[i];
      sb += b0[i] * b0[i] + b1[i] * b1[i] + b2[i] * b2[i] + b3[i] * b3[i];
    }
    sa += __shfl_xor(sa, 16, 64); sa += __shfl_xor(sa, 32, 64);
    sb += __shfl_xor(sb, 16, 64); sb += __shfl_xor(sb, 32, 64);
    zza = sa; zzb = sb;
  }

  unsigned rka = 0xFFFFFFFFu, rkb = 0xFFFFFFFFu;
  const unsigned kj0 = (unsigned)(ksl * 4), kj1 = kj0 + 1, kj2 = kj0 + 2, kj3 = kj0 + 3;

  for (int ph = 0; ph < 8; ++ph) {
    // current phase's 2 staging loads done; next phase's stay in flight
    if (ph < 7) { asm volatile("s_waitcnt vmcnt(2)" ::: "memory"); }
    else        { asm volatile("s_waitcnt vmcnt(0)" ::: "memory"); }
    __builtin_amdgcn_sched_barrier(0);
    __builtin_amdgcn_s_barrier();       // all waves done reading buf[(ph+2)%3]
    if (ph < 6) STAGE(ph + 2, (ph + 2) % 3);
    const bf16x8* sfrag = (const bf16x8*)(smfrag[ph % 3]);
    __builtin_amdgcn_s_setprio(1);
#pragma unroll
    for (int tt = 0; tt < 8; ++tt) {
      const int g = ph * 8 + tt;        // global code tile
      bf16x8 e0 = sfrag[(tt * 2 + 0) * 64 + lane];   // conflict-free b128
      bf16x8 e1 = sfrag[(tt * 2 + 1) * 64 + lane];
      const f32x4 ee = *(const f32x4*)(see + g * 16 + ksl * 4);
      f32x4 a = __builtin_amdgcn_mfma_f32_16x16x32_bf16(e0, zfa0, ee, 0, 0, 0);
      a = __builtin_amdgcn_mfma_f32_16x16x32_bf16(e1, zfa1, a, 0, 0, 0);
      f32x4 b = __builtin_amdgcn_mfma_f32_16x16x32_bf16(e0, zfb0, ee, 0, 0, 0);
      b = __builtin_amdgcn_mfma_f32_16x16x32_bf16(e1, zfb1, b, 0, 0, 0);
      const unsigned g16 = (unsigned)(g * 16);
      {
        const unsigned q0 = (__float_as_uint(a[0]) << 10) + kj0;
        const unsigned q1 = (__float_as_uint(a[1]) << 10) + kj1;
        const unsigned q2 = (__float_as_uint(a[2]) << 10) + kj2;
        const unsigned q3 = (__float_as_uint(a[3]) << 10) + kj3;
        rka = min(rka, min(min(q0, q1), min(q2, q3)) + g16);
      }
      {
        const unsigned q0 = (__float_as_uint(b[0]) << 10) + kj0;
        const unsigned q1 = (__float_as_uint(b[1]) << 10) + kj1;
        const unsigned q2 = (__float_as_uint(b[2]) << 10) + kj2;
        const unsigned q3 = (__float_as_uint(b[3]) << 10) + kj3;
        rkb = min(rkb, min(min(q0, q1), min(q2, q3)) + g16);
      }
    }
    __builtin_amdgcn_s_setprio(0);
  }
#undef STAGE

  // per-row final keys: reduce across the 4 ksl lane groups
  rka = min(rka, (unsigned)__shfl_xor((int)rka, 16, 64));
  rka = min(rka, (unsigned)__shfl_xor((int)rka, 32, 64));
  rkb = min(rkb, (unsigned)__shfl_xor((int)rkb, 16, 64));
  rkb = min(rkb, (unsigned)__shfl_xor((int)rkb, 32, 64));

  // fused epilogue: 2 lanes per row (erow 0..31), gather z_q, write idx,
  // accumulate loss/var partials.
  const int erow = lane >> 1, eseg = lane & 1;
  const int src = erow & 15;   // lane in ksl-group 0 holding this row's key
  const unsigned ka = (unsigned)__shfl((int)rka, src, 64);
  const unsigned kb = (unsigned)__shfl((int)rkb, src, 64);
  const float za = __shfl(zza, src, 64);
  const float zb = __shfl(zzb, src, 64);
  const unsigned k = (erow < 16) ? ka : kb;
  const float zzv = (erow < 16) ? za : zb;
  const unsigned idx = k & 1023u;
  const size_t rowg = (size_t)row_base + erow;
  const f32x4* ep = (const f32x4*)(emb + (size_t)idx * 64 + eseg * 32);
  f32x4* op = (f32x4*)(out + rowg * 64 + eseg * 32);
#pragma unroll
  for (int c = 0; c < 8; ++c) op[c] = ep[c];

  float ls = 0.f; int s1 = 0, s2 = 0;
  if (eseg == 0) {
    // recover exact t = 0.875 + ee - 2 z.e : exp(126) | mant22 | (key>>10)
    ls = zzv + __uint_as_float(0x3F400000u | (k >> 10)) - 0.875f;
    s1 = (int)idx;
    s2 = (int)(idx * idx);
    out[OUT_IDX + rowg] = (float)idx;
  }
#pragma unroll
  for (int off = 1; off < 64; off <<= 1) {
    ls += __shfl_xor(ls, off, 64);
    s1 += __shfl_xor(s1, off, 64);
    s2 += __shfl_xor(s2, off, 64);
  }
  if (lane == 0) { sL[wave] = ls; sA[wave] = s1; sB[wave] = s2; }
  __syncthreads();
  if (tid == 0) {
    float L = 0; int a = 0, b = 0;
#pragma unroll
    for (int w = 0; w < 8; ++w) { L += sL[w]; a += sA[w]; b += sB[w]; }
    ((float*)(ws + WS_LOSS))[blockIdx.x] = L;
    ((int*)(ws + WS_S1))[blockIdx.x] = a;
    ((int*)(ws + WS_S2))[blockIdx.x] = b;
  }
}

// ---- K2: final scalar reduce over 512 block partials ----------------------
__global__ void vq_final(float* __restrict__ out, const char* __restrict__ ws) {
  const int t = threadIdx.x;   // 256 threads
  const float* lp = (const float*)(ws + WS_LOSS);
  const int* p1 = (const int*)(ws + WS_S1);
  const int* p2 = (const int*)(ws + WS_S2);
  double L = 0; long long a = 0, b = 0;
#pragma unroll
  for (int kk = 0; kk < 2; ++kk) {
    const int i = t + 256 * kk;
    L += (double)lp[i];
    a += (long long)p1[i];
    b += (long long)p2[i];
  }
#pragma unroll
  for (int off = 1; off < 64; off <<= 1) {
    L += __shfl_xor(L, off, 64);
    a += __shfl_xor(a, off, 64);
    b += __shfl_xor(b, off, 64);
  }
  __shared__ double sLf[4];
  __shared__ long long sAf[4], sBf[4];
  const int wave = t >> 6, lane = t & 63;
  if (lane == 0) { sLf[wave] = L; sAf[wave] = a; sBf[wave] = b; }
  __syncthreads();
  if (t == 0) {
    double Lt = 0; long long at = 0, bt = 0;
#pragma unroll
    for (int w = 0; w < 4; ++w) { Lt += sLf[w]; at += sAf[w]; bt += sBf[w]; }
    // loss = (beta + 1) * mean((z_q - z)^2), beta = 0.25
    out[OUT_LOSS] = (float)(1.25 * Lt / 8388608.0);
    // var(idx, ddof=1) exact: (n*S2 - S1^2) / (n*(n-1))
    long long num = bt * 131072LL - at * at;
    out[OUT_VAR] = (float)((double)num / (131072.0 * 131071.0));
  }
}

extern "C" void kernel_launch(void* const* d_in, const int* in_sizes, int n_in,
                              void* d_out, int out_size, void* d_ws, size_t ws_size,
                              hipStream_t stream) {
  (void)in_sizes; (void)n_in; (void)out_size; (void)ws_size;
  const float* z = (const float*)d_in[0];
  const float* emb = (const float*)d_in[1];
  float* out = (float*)d_out;
  char* ws = (char*)d_ws;
  vq_prep<<<64, 64, 0, stream>>>(emb, ws);
  vq_main<<<512, 512, 0, stream>>>(z, emb, out, ws);
  vq_final<<<1, 256, 0, stream>>>(out, ws);
}